// Round 4
// baseline (272.141 us; speedup 1.0000x reference)
//
#include <hip/hip_runtime.h>

// Sparse 2:4 grouped conv, MI355X.  R4: double-buffered LDS in conv — issue
// global_load_lds for step s+1, compute step s, THEN barrier, so the vmcnt(0)
// drain overlaps ~400 cyc of MFMA. 19 barriers/block (was 36).

#define INF   1152
#define HO    56
#define LOUT  3136      // 56*56
#define XP    58        // padded spatial

typedef __attribute__((ext_vector_type(8))) short bf16x8;
typedef __attribute__((ext_vector_type(4))) float f32x4;

__device__ __forceinline__ unsigned short f2bf(float f) {
  union { float f; unsigned u; } v; v.f = f;
  unsigned r = v.u + 0x7fffu + ((v.u >> 16) & 1u);   // RNE
  return (unsigned short)(r >> 16);
}

__device__ __forceinline__ void async_load16(const void* g, void* l) {
  __builtin_amdgcn_global_load_lds(
      (const __attribute__((address_space(1))) void*)g,
      (__attribute__((address_space(3))) void*)l, 16, 0, 0);
}

// ---------------- fused prep: pad+transpose+cast x  |  gumbel+mask+pack W ------
__global__ __launch_bounds__(256) void prep_kernel(
    const float* __restrict__ x, const float* __restrict__ Ws,
    const float* __restrict__ cw, const float* __restrict__ gb,
    const float* __restrict__ pat,
    unsigned short* __restrict__ Xt, unsigned short* __restrict__ Wt) {
  __shared__ float lds[56 * 129];
  const int t   = threadIdx.x;
  const int bid = blockIdx.x;

  if (bid >= 3712) {                                 // ---- weight pack ----
    int idx = (bid - 3712) * 256 + t;                // 294912 total
    int c   = idx & 127;
    int of  = (idx >> 7) & 127;
    int gt  = idx >> 14;                             // g*9+tap
    int g   = gt / 9;
    int tap = gt - g * 9;
    int e   = ((g << 7) + of) * INF + c * 9 + tap;
    int q   = e >> 2, pos = e & 3;
    const float* cq = cw + q * 6;
    const float* gq = gb + q * 6;
    float best = cq[0] + gq[0]; int bi = 0;
    #pragma unroll
    for (int j = 1; j < 6; ++j) {
      float v2 = cq[j] + gq[j];
      if (v2 > best) { best = v2; bi = j; }          // strict > = first-max
    }
    Wt[idx] = f2bf(Ws[e] * pat[bi * 4 + pos]);
    return;
  }

  // ---- xpose: x (B,256,56,56) f32 -> Xt[bg][58][58][c=128] bf16, zero borders
  const int bg  = bid / 58;
  const int ihp = bid - bg * 58;
  uint4* dst = (uint4*)(Xt + ((bg * XP + ihp) * XP) * 128);
  if (ihp == 0 || ihp == XP - 1) {
    const uint4 z = {0u, 0u, 0u, 0u};
    for (int i = t; i < XP * 16; i += 256) dst[i] = z;
    return;
  }
  const int ih = ihp - 1;
  const float4* src = (const float4*)(x + (bg * 128) * LOUT + ih * HO);
  for (int i = t; i < 128 * 14; i += 256) {
    int c = i / 14, seg = i - c * 14;                // iw = seg*4
    float4 v = src[c * (LOUT / 4) + seg];
    float* row = &lds[(seg * 4) * 129 + c];
    row[0]       = v.x;
    row[129]     = v.y;
    row[2 * 129] = v.z;
    row[3 * 129] = v.w;
  }
  __syncthreads();
  for (int i = t; i < XP * 16; i += 256) {
    int iwp = i >> 4, oct = i & 15;
    uint4 val = {0u, 0u, 0u, 0u};
    if (iwp != 0 && iwp != XP - 1) {
      const float* s = &lds[(iwp - 1) * 129 + (oct << 3)];
      val.x = (unsigned)f2bf(s[0]) | ((unsigned)f2bf(s[1]) << 16);
      val.y = (unsigned)f2bf(s[2]) | ((unsigned)f2bf(s[3]) << 16);
      val.z = (unsigned)f2bf(s[4]) | ((unsigned)f2bf(s[5]) << 16);
      val.w = (unsigned)f2bf(s[6]) | ((unsigned)f2bf(s[7]) << 16);
    }
    dst[i] = val;
  }
}

// per-step global offsets: 18 steps = 9 taps x 2 c-halves
__device__ __forceinline__ void step_offs(int s, int g, int& aOff, int& bOff) {
  const int tap = s >> 1, kc = s & 1;
  const int th = tap / 3, tw = tap - th * 3;
  aOff = ((g * 9 + tap) << 14) + (kc << 6);
  bOff = ((th * XP + tw) << 7) + (kc << 6);
}

// ---------------- conv: implicit-GEMM, BK=64, double-buffered LDS -------------
// LDS row = 64 c = 8 chunks of 16B; chunk (row,ch) stored at slot ch^(row&7).
__global__ __launch_bounds__(256, 2) void conv_mfma_kernel(
    const unsigned short* __restrict__ Wt, const unsigned short* __restrict__ Xt,
    float* __restrict__ out) {
  __shared__ __align__(16) unsigned short sA[2][128 * 64];   // 2 x 16 KB
  __shared__ __align__(16) unsigned short sB[2][128 * 64];   // 2 x 16 KB
  const int t  = threadIdx.x;
  const int ln = t & 63, wv = t >> 6;
  const int wm = wv >> 1, wn = wv & 1;
  const int col = ln & 15, kq = ln >> 4, c7 = col & 7;

  // XCD-aware swizzle: contiguous bg range per XCD for L2 locality
  const int lid   = blockIdx.y * 25 + blockIdx.x;
  const int v     = (lid & 7) * 200 + (lid >> 3);
  const int bg    = v / 25;
  const int tileN = v - bg * 25;
  const int g     = bg & 1;
  const int l0    = tileN << 7;

  // staging geometry (fixed per thread): 8-row issue groups, xor'd chunk
  const int r8 = ln >> 3;
  const int ch = (ln & 7) ^ r8;
  int arow[4], brow[4], lbs[4];
  #pragma unroll
  for (int i = 0; i < 4; ++i) {
    const int rr = (wv << 5) + (i << 3) + r8;      // 0..127
    arow[i] = (rr << 7) + (ch << 3);               // of*128 + c
    int ll = l0 + rr;
    if (ll > LOUT - 1) ll = LOUT - 1;              // tail tile: clamp
    int oh = ll / HO, ow = ll - oh * HO;
    brow[i] = ((bg * XP + oh) * XP + ow) * 128 + (ch << 3);
    lbs[i]  = ((wv << 5) + (i << 3)) << 6;         // LDS elem base of issue
  }

  f32x4 acc[4][4];
  #pragma unroll
  for (int i = 0; i < 4; ++i)
    #pragma unroll
    for (int j = 0; j < 4; ++j) acc[i][j] = (f32x4){0.f, 0.f, 0.f, 0.f};

  // prologue: stage step 0 into buf 0
  {
    int aOff, bOff;
    step_offs(0, g, aOff, bOff);
    #pragma unroll
    for (int i = 0; i < 4; ++i) {
      async_load16(Wt + aOff + arow[i], &sA[0][lbs[i]]);
      async_load16(Xt + bOff + brow[i], &sB[0][lbs[i]]);
    }
  }
  __syncthreads();

  #pragma unroll 1
  for (int s = 0; s < 18; ++s) {
    const int buf = s & 1;
    if (s < 17) {                                   // issue next step -> buf^1
      int aOff, bOff;
      step_offs(s + 1, g, aOff, bOff);
      #pragma unroll
      for (int i = 0; i < 4; ++i) {
        async_load16(Wt + aOff + arow[i], &sA[buf ^ 1][lbs[i]]);
        async_load16(Xt + bOff + brow[i], &sB[buf ^ 1][lbs[i]]);
      }
    }
    // compute current step from buf — overlaps the in-flight loads
    #pragma unroll
    for (int kh = 0; kh < 2; ++kh) {
      const int pk = (((kh << 2) + kq) ^ c7) << 3;
      bf16x8 af[4], bfr[4];
      #pragma unroll
      for (int mi = 0; mi < 4; ++mi)
        af[mi] = *(const bf16x8*)&sA[buf][(((wm << 6) + (mi << 4) + col) << 6) + pk];
      #pragma unroll
      for (int ni = 0; ni < 4; ++ni)
        bfr[ni] = *(const bf16x8*)&sB[buf][(((wn << 6) + (ni << 4) + col) << 6) + pk];
      #pragma unroll
      for (int mi = 0; mi < 4; ++mi)
        #pragma unroll
        for (int ni = 0; ni < 4; ++ni)
          acc[mi][ni] = __builtin_amdgcn_mfma_f32_16x16x32_bf16(
              af[mi], bfr[ni], acc[mi][ni], 0, 0, 0);
    }
    __syncthreads();                                // drain lands after compute
  }

  // epilogue: C/D layout col=lane&15, row=(lane>>4)*4+reg
  const int rowq = kq << 2;
  #pragma unroll
  for (int mi = 0; mi < 4; ++mi) {
    #pragma unroll
    for (int ni = 0; ni < 4; ++ni) {
      const int l = l0 + (wn << 6) + (ni << 4) + col;
      if (l < LOUT) {
        #pragma unroll
        for (int r = 0; r < 4; ++r) {
          const int of = (wm << 6) + (mi << 4) + rowq + r;
          out[(bg * 128 + of) * LOUT + l] = acc[mi][ni][r];
        }
      }
    }
  }
}

extern "C" void kernel_launch(void* const* d_in, const int* in_sizes, int n_in,
                              void* d_out, int out_size, void* d_ws, size_t ws_size,
                              hipStream_t stream) {
  const float* x   = (const float*)d_in[0];
  const float* Ws  = (const float*)d_in[1];
  const float* cw  = (const float*)d_in[2];
  const float* gb  = (const float*)d_in[3];
  const float* pat = (const float*)d_in[4];
  float* out = (float*)d_out;

  unsigned short* Wt = (unsigned short*)d_ws;                       // 576 KB
  unsigned short* Xt = (unsigned short*)((char*)d_ws + (1 << 20));  // 52.6 MB

  prep_kernel<<<4864, 256, 0, stream>>>(x, Ws, cw, gb, pat, Xt, Wt);
  conv_mfma_kernel<<<dim3(25, 64), 256, 0, stream>>>(Wt, Xt, out);
}

// Round 5
// 261.026 us; speedup vs baseline: 1.0426x; 1.0426x over previous
//
#include <hip/hip_runtime.h>

// Sparse 2:4 grouped conv, MI355X.  R5: revert dbuf (R4 occupancy cliff),
// R3 single-buffered BK=64 structure + 32x32x16 MFMA (2382 vs 2075 TF ceiling,
// half the MFMA issue slots per BK-step).

#define INF   1152
#define HO    56
#define LOUT  3136      // 56*56
#define XP    58        // padded spatial

typedef __attribute__((ext_vector_type(8))) short bf16x8;
typedef __attribute__((ext_vector_type(16))) float f32x16;

__device__ __forceinline__ unsigned short f2bf(float f) {
  union { float f; unsigned u; } v; v.f = f;
  unsigned r = v.u + 0x7fffu + ((v.u >> 16) & 1u);   // RNE
  return (unsigned short)(r >> 16);
}

__device__ __forceinline__ void async_load16(const void* g, void* l) {
  __builtin_amdgcn_global_load_lds(
      (const __attribute__((address_space(1))) void*)g,
      (__attribute__((address_space(3))) void*)l, 16, 0, 0);
}

// ---------------- fused prep: pad+transpose+cast x  |  gumbel+mask+pack W ------
__global__ __launch_bounds__(256) void prep_kernel(
    const float* __restrict__ x, const float* __restrict__ Ws,
    const float* __restrict__ cw, const float* __restrict__ gb,
    const float* __restrict__ pat,
    unsigned short* __restrict__ Xt, unsigned short* __restrict__ Wt) {
  __shared__ float lds[56 * 129];
  const int t   = threadIdx.x;
  const int bid = blockIdx.x;

  if (bid >= 3712) {                                 // ---- weight pack ----
    int idx = (bid - 3712) * 256 + t;                // 294912 total
    int c   = idx & 127;
    int of  = (idx >> 7) & 127;
    int gt  = idx >> 14;                             // g*9+tap
    int g   = gt / 9;
    int tap = gt - g * 9;
    int e   = ((g << 7) + of) * INF + c * 9 + tap;
    int q   = e >> 2, pos = e & 3;
    const float* cq = cw + q * 6;
    const float* gq = gb + q * 6;
    float best = cq[0] + gq[0]; int bi = 0;
    #pragma unroll
    for (int j = 1; j < 6; ++j) {
      float v2 = cq[j] + gq[j];
      if (v2 > best) { best = v2; bi = j; }          // strict > = first-max
    }
    Wt[idx] = f2bf(Ws[e] * pat[bi * 4 + pos]);
    return;
  }

  // ---- xpose: x (B,256,56,56) f32 -> Xt[bg][58][58][c=128] bf16, zero borders
  const int bg  = bid / 58;
  const int ihp = bid - bg * 58;
  uint4* dst = (uint4*)(Xt + ((bg * XP + ihp) * XP) * 128);
  if (ihp == 0 || ihp == XP - 1) {
    const uint4 z = {0u, 0u, 0u, 0u};
    for (int i = t; i < XP * 16; i += 256) dst[i] = z;
    return;
  }
  const int ih = ihp - 1;
  const float4* src = (const float4*)(x + (bg * 128) * LOUT + ih * HO);
  for (int i = t; i < 128 * 14; i += 256) {
    int c = i / 14, seg = i - c * 14;                // iw = seg*4
    float4 v = src[c * (LOUT / 4) + seg];
    float* row = &lds[(seg * 4) * 129 + c];
    row[0]       = v.x;
    row[129]     = v.y;
    row[2 * 129] = v.z;
    row[3 * 129] = v.w;
  }
  __syncthreads();
  for (int i = t; i < XP * 16; i += 256) {
    int iwp = i >> 4, oct = i & 15;
    uint4 val = {0u, 0u, 0u, 0u};
    if (iwp != 0 && iwp != XP - 1) {
      const float* s = &lds[(iwp - 1) * 129 + (oct << 3)];
      val.x = (unsigned)f2bf(s[0]) | ((unsigned)f2bf(s[1]) << 16);
      val.y = (unsigned)f2bf(s[2]) | ((unsigned)f2bf(s[3]) << 16);
      val.z = (unsigned)f2bf(s[4]) | ((unsigned)f2bf(s[5]) << 16);
      val.w = (unsigned)f2bf(s[6]) | ((unsigned)f2bf(s[7]) << 16);
    }
    dst[i] = val;
  }
}

// ---------------- conv: implicit-GEMM, BK=64 single-buffer, 32x32x16 MFMA -----
// LDS row = 64 c = 8 chunks of 16B; chunk (row,ch) stored at slot ch^(row&7).
// Staging identical to R3. Reads: A[m=ln&31][k=8*(ln>>5)+j] per 16-k step.
__global__ __launch_bounds__(256, 4) void conv_mfma_kernel(
    const unsigned short* __restrict__ Wt, const unsigned short* __restrict__ Xt,
    float* __restrict__ out) {
  __shared__ __align__(16) unsigned short sA[128 * 64];   // 16 KB
  __shared__ __align__(16) unsigned short sB[128 * 64];   // 16 KB
  const int t  = threadIdx.x;
  const int ln = t & 63, wv = t >> 6;
  const int wm = wv >> 1, wn = wv & 1;
  const int col32 = ln & 31, kh2 = ln >> 5;

  // XCD-aware swizzle: contiguous bg range per XCD for L2 locality
  const int lid   = blockIdx.y * 25 + blockIdx.x;
  const int v     = (lid & 7) * 200 + (lid >> 3);
  const int bg    = v / 25;
  const int tileN = v - bg * 25;
  const int g     = bg & 1;
  const int l0    = tileN << 7;

  // staging geometry (fixed per thread): 8-row issue groups, xor'd chunk
  const int r8 = ln >> 3;
  const int ch = (ln & 7) ^ r8;
  int arow[4], brow[4], lbs[4];
  #pragma unroll
  for (int i = 0; i < 4; ++i) {
    const int rr = (wv << 5) + (i << 3) + r8;      // 0..127
    arow[i] = (rr << 7) + (ch << 3);               // of*128 + c
    int ll = l0 + rr;
    if (ll > LOUT - 1) ll = LOUT - 1;              // tail tile: clamp
    int oh = ll / HO, ow = ll - oh * HO;
    brow[i] = ((bg * XP + oh) * XP + ow) * 128 + (ch << 3);
    lbs[i]  = ((wv << 5) + (i << 3)) << 6;         // LDS elem base of issue
  }

  f32x16 acc[2][2];
  #pragma unroll
  for (int i = 0; i < 2; ++i)
    #pragma unroll
    for (int j = 0; j < 2; ++j)
      #pragma unroll
      for (int r = 0; r < 16; ++r) acc[i][j][r] = 0.f;

  for (int tap = 0; tap < 9; ++tap) {
    const int th = tap / 3, tw = tap - th * 3;
    const int bTap = (th * XP + tw) << 7;
    const int aTap = (g * 9 + tap) << 14;
    #pragma unroll 1
    for (int kc = 0; kc < 2; ++kc) {
      const int c0 = kc << 6;
      __syncthreads();                             // prior reads done
      #pragma unroll
      for (int i = 0; i < 4; ++i) {
        async_load16(Wt + aTap + c0 + arow[i], &sA[lbs[i]]);
        async_load16(Xt + bTap + c0 + brow[i], &sB[lbs[i]]);
      }
      __syncthreads();                             // drains vmcnt
      #pragma unroll
      for (int kh = 0; kh < 4; ++kh) {
        // logical 16B chunk for this lane's 8 k's; row&7 == col32&7
        const int pk = (((kh << 1) + kh2) ^ (col32 & 7)) << 3;
        bf16x8 af[2], bfr[2];
        #pragma unroll
        for (int mi = 0; mi < 2; ++mi)
          af[mi] = *(const bf16x8*)&sA[(((wm << 6) + (mi << 5) + col32) << 6) + pk];
        #pragma unroll
        for (int ni = 0; ni < 2; ++ni)
          bfr[ni] = *(const bf16x8*)&sB[(((wn << 6) + (ni << 5) + col32) << 6) + pk];
        #pragma unroll
        for (int mi = 0; mi < 2; ++mi)
          #pragma unroll
          for (int ni = 0; ni < 2; ++ni)
            acc[mi][ni] = __builtin_amdgcn_mfma_f32_32x32x16_bf16(
                af[mi], bfr[ni], acc[mi][ni], 0, 0, 0);
      }
    }
  }

  // epilogue: 32x32 C/D layout col=lane&31, row=(reg&3)+8*(reg>>2)+4*(lane>>5)
  const int rbase = kh2 << 2;
  #pragma unroll
  for (int mi = 0; mi < 2; ++mi) {
    #pragma unroll
    for (int ni = 0; ni < 2; ++ni) {
      const int l = l0 + (wn << 6) + (ni << 5) + col32;
      if (l < LOUT) {
        #pragma unroll
        for (int r = 0; r < 16; ++r) {
          const int of = (wm << 6) + (mi << 5) + (r & 3) + ((r >> 2) << 3) + rbase;
          out[(bg * 128 + of) * LOUT + l] = acc[mi][ni][r];
        }
      }
    }
  }
}

extern "C" void kernel_launch(void* const* d_in, const int* in_sizes, int n_in,
                              void* d_out, int out_size, void* d_ws, size_t ws_size,
                              hipStream_t stream) {
  const float* x   = (const float*)d_in[0];
  const float* Ws  = (const float*)d_in[1];
  const float* cw  = (const float*)d_in[2];
  const float* gb  = (const float*)d_in[3];
  const float* pat = (const float*)d_in[4];
  float* out = (float*)d_out;

  unsigned short* Wt = (unsigned short*)d_ws;                       // 576 KB
  unsigned short* Xt = (unsigned short*)((char*)d_ws + (1 << 20));  // 52.6 MB

  prep_kernel<<<4864, 256, 0, stream>>>(x, Ws, cw, gb, pat, Xt, Wt);
  conv_mfma_kernel<<<dim3(25, 64), 256, 0, stream>>>(Wt, Xt, out);
}